// Round 12
// baseline (143.085 us; speedup 1.0000x reference)
//
#include <hip/hip_runtime.h>
#include <hip/hip_bf16.h>
#include <math.h>

typedef float v4f __attribute__((ext_vector_type(4)));
typedef short bf16x8 __attribute__((ext_vector_type(8)));   // 8 bf16 (4 VGPR)
typedef float f32x16 __attribute__((ext_vector_type(16)));

#define BATCH 4
#define NQ 4096
#define NK 4096
#define DIM 256
#define INNER 64
#define NEG_INF (-3.0e38f)
#define CAP 64

// ---------- K1: fused q/k projection + bulk output zero-fill -----------------
// grid 1024: bid<512 -> q slab (row-major bf16), else k slab (fragment-major
// bf16: [tile32][d:4][hi:2][row:32][e:8]). Values bit-identical to r2-r11.
// Tail: grid-stride zero-fill of the whole 268MB output (no dependent loads
// follow -> stores drain at fill rate, uncoupled from any compute).
__global__ __launch_bounds__(256) void proj_kernel(
    const float* __restrict__ q, const float* __restrict__ k,
    const float* __restrict__ Wq, const float* __restrict__ Wk,
    float* __restrict__ qh, float* __restrict__ kh,
    ushort* __restrict__ qhb, ushort* __restrict__ khb,
    float* __restrict__ outz)
{
  __shared__ float xs[32 * 260];
  const int bid = blockIdx.x;
  const bool isq = bid < 512;
  const float* X   = isq ? q : k;
  const float* W   = isq ? Wq : Wk;
  float*   out     = isq ? qh : kh;
  const float scale = isq ? 0.125f : 1.0f;
  const int row0 = (isq ? bid : bid - 512) * 32;
  const int t = threadIdx.x;

  #pragma unroll
  for (int it = 0; it < 8; ++it) {
    int idx = it * 256 + t;
    int r = idx >> 6, dq = idx & 63;
    v4f v = *reinterpret_cast<const v4f*>(X + (size_t)(row0 + r) * DIM + dq * 4);
    *reinterpret_cast<v4f*>(&xs[r * 260 + dq * 4]) = v;
  }
  __syncthreads();

  const int i0 = (t & 15) * 4;
  const int rg = t >> 4;
  float acc[2][4];
  #pragma unroll
  for (int p = 0; p < 2; ++p)
    #pragma unroll
    for (int i = 0; i < 4; ++i) acc[p][i] = 0.f;

  for (int d0 = 0; d0 < DIM; d0 += 4) {
    v4f w0 = *reinterpret_cast<const v4f*>(W + (d0 + 0) * INNER + i0);
    v4f w1 = *reinterpret_cast<const v4f*>(W + (d0 + 1) * INNER + i0);
    v4f w2 = *reinterpret_cast<const v4f*>(W + (d0 + 2) * INNER + i0);
    v4f w3 = *reinterpret_cast<const v4f*>(W + (d0 + 3) * INNER + i0);
    #pragma unroll
    for (int p = 0; p < 2; ++p) {
      v4f x = *reinterpret_cast<const v4f*>(&xs[(rg + 16 * p) * 260 + d0]);
      #pragma unroll
      for (int i = 0; i < 4; ++i) {
        float bs = x[0] * w0[i];                 // bit-exact blocked order
        bs = fmaf(x[1], w1[i], bs);
        bs = fmaf(x[2], w2[i], bs);
        bs = fmaf(x[3], w3[i], bs);
        acc[p][i] += bs;
      }
    }
  }

  const int d  = i0 >> 4;            // dim-group 0..3
  const int hi = (i0 >> 3) & 1;      // half 0..1
  const int e0 = i0 & 7;             // 0 or 4
  #pragma unroll
  for (int p = 0; p < 2; ++p) {
    v4f o;
    ushort ob[4];
    #pragma unroll
    for (int i = 0; i < 4; ++i) {
      o[i] = acc[p][i] * scale;
      __hip_bfloat16 h = __float2bfloat16(o[i]);
      ob[i] = *reinterpret_cast<ushort*>(&h);
    }
    int rr = rg + 16 * p;
    size_t row = (size_t)(row0 + rr);
    *reinterpret_cast<v4f*>(out + row * INNER + i0) = o;
    if (isq) {
      *reinterpret_cast<uint2*>(qhb + row * INNER + i0) =
          *reinterpret_cast<uint2*>(ob);
    } else {
      size_t off = (size_t)(bid - 512) * 2048 + d * 512 + hi * 256 + rr * 8 + e0;
      *reinterpret_cast<uint2*>(khb + off) = *reinterpret_cast<uint2*>(ob);
    }
  }

  // ---- bulk zero-fill of d_out (268 MB, grid-stride, coalesced v4f) -------
  {
    v4f* zp = reinterpret_cast<v4f*>(outz);
    const v4f z = {0.f, 0.f, 0.f, 0.f};
    size_t idx = (size_t)bid * 256 + t;          // 262144 threads
    #pragma unroll 4
    for (int it = 0; it < 64; ++it)
      zp[idx + (size_t)it * 262144] = z;
  }
}

// ---------- cold-path sorted inserts -----------------------------------------
__device__ __forceinline__ void insert5(float (&v)[5], int (&ix)[5], float x, int xi) {
  bool g0 = x > v[0], g1 = x > v[1], g2 = x > v[2], g3 = x > v[3];
  v[4]  = g3 ? v[3] : x;                 ix[4] = g3 ? ix[3] : xi;
  v[3]  = g3 ? (g2 ? v[2] : x) : v[3];   ix[3] = g3 ? (g2 ? ix[2] : xi) : ix[3];
  v[2]  = g2 ? (g1 ? v[1] : x) : v[2];   ix[2] = g2 ? (g1 ? ix[1] : xi) : ix[2];
  v[1]  = g1 ? (g0 ? v[0] : x) : v[1];   ix[1] = g1 ? (g0 ? ix[0] : xi) : ix[1];
  v[0]  = g0 ? x : v[0];                 ix[0] = g0 ? xi : ix[0];
}

// value-only top-8 insert (cold; precondition x > v[7])
__device__ __forceinline__ void insert8v(float (&v)[8], float x) {
  bool g0 = x > v[0], g1 = x > v[1], g2 = x > v[2], g3 = x > v[3];
  bool g4 = x > v[4], g5 = x > v[5], g6 = x > v[6];
  v[7] = g6 ? v[6] : x;
  v[6] = g6 ? (g5 ? v[5] : x) : v[6];
  v[5] = g5 ? (g4 ? v[4] : x) : v[5];
  v[4] = g4 ? (g3 ? v[3] : x) : v[4];
  v[3] = g3 ? (g2 ? v[2] : x) : v[3];
  v[2] = g2 ? (g1 ? v[1] : x) : v[2];
  v[1] = g1 ? (g0 ? v[0] : x) : v[1];
  v[0] = g0 ? x : v[0];
}

// ---------- K2: 2-pass MFMA filter + exact rescore + sparse scatter ----------
// 512 thr = 8 waves; block owns 32 q-rows. khb fragment-major (coalesced 1KB
// fragment loads). Zeros already written by proj (stream order) -> this kernel
// writes only the <=160 weight dwords per block.
__global__ __launch_bounds__(512) void filter_kernel(
    const ushort* __restrict__ qhb, const ushort* __restrict__ khb,
    const float* __restrict__ qh, const float* __restrict__ kh,
    float* __restrict__ out)
{
  __shared__ float qhf[32][68];
  __shared__ float sm[32][16];
  __shared__ float tau[32];
  __shared__ int   cnt[32];
  __shared__ int   cand[32][CAP];
  __shared__ float exactv[32][CAP];
  __shared__ float w5[32][5];
  __shared__ int   id5[32][6];

  const int t   = threadIdx.x;
  const int bid = blockIdx.x;
  const int wg  = (bid & 7) * 64 + (bid >> 3);   // XCD swizzle (512 = 8*64)
  const int b   = wg >> 7;
  const int q0  = (wg & 127) * 32;
  const int qg  = t >> 6;                        // wave 0..7
  const int kg  = t & 63;                        // lane
  const int ln  = kg & 31;
  const int hi  = kg >> 5;

  if (t < 256) {
    int row = t >> 3, c8 = (t & 7) * 8;
    const float* src = qh + ((size_t)b * NQ + q0 + row) * INNER + c8;
    *reinterpret_cast<v4f*>(&qhf[row][c8])     = *reinterpret_cast<const v4f*>(src);
    *reinterpret_cast<v4f*>(&qhf[row][c8 + 4]) = *reinterpret_cast<const v4f*>(src + 4);
  }
  if (t < 32) cnt[t] = 0;

  const ushort* qptr = qhb + ((size_t)b * NQ + q0 + ln) * INNER + hi * 8;
  bf16x8 qf0 = *reinterpret_cast<const bf16x8*>(qptr);
  bf16x8 qf1 = *reinterpret_cast<const bf16x8*>(qptr + 16);
  bf16x8 qf2 = *reinterpret_cast<const bf16x8*>(qptr + 32);
  bf16x8 qf3 = *reinterpret_cast<const bf16x8*>(qptr + 48);

  const ushort* ktile = khb + ((size_t)b * 128 + qg * 16) * 2048;

  // ---- Pass 1: branchless strip max --------------------------------------
  float smax = NEG_INF;
  for (int t16 = 0; t16 < 16; ++t16) {
    const ushort* tb = ktile + (size_t)t16 * 2048;
    bf16x8 k0 = *reinterpret_cast<const bf16x8*>(tb +        kg * 8);
    bf16x8 k1 = *reinterpret_cast<const bf16x8*>(tb +  512 + kg * 8);
    bf16x8 k2 = *reinterpret_cast<const bf16x8*>(tb + 1024 + kg * 8);
    bf16x8 k3 = *reinterpret_cast<const bf16x8*>(tb + 1536 + kg * 8);

    f32x16 acc = {0.f, 0.f, 0.f, 0.f, 0.f, 0.f, 0.f, 0.f,
                  0.f, 0.f, 0.f, 0.f, 0.f, 0.f, 0.f, 0.f};
    acc = __builtin_amdgcn_mfma_f32_32x32x16_bf16(k0, qf0, acc, 0, 0, 0);
    acc = __builtin_amdgcn_mfma_f32_32x32x16_bf16(k1, qf1, acc, 0, 0, 0);
    acc = __builtin_amdgcn_mfma_f32_32x32x16_bf16(k2, qf2, acc, 0, 0, 0);
    acc = __builtin_amdgcn_mfma_f32_32x32x16_bf16(k3, qf3, acc, 0, 0, 0);

    float m0 = fmaxf(fmaxf(acc[0],  acc[1]),  fmaxf(acc[2],  acc[3]));
    float m1 = fmaxf(fmaxf(acc[4],  acc[5]),  fmaxf(acc[6],  acc[7]));
    float m2 = fmaxf(fmaxf(acc[8],  acc[9]),  fmaxf(acc[10], acc[11]));
    float m3 = fmaxf(fmaxf(acc[12], acc[13]), fmaxf(acc[14], acc[15]));
    smax = fmaxf(smax, fmaxf(fmaxf(m0, m1), fmaxf(m2, m3)));
  }
  sm[ln][qg * 2 + hi] = smax;
  __syncthreads();

  if (t < 32) {
    float rv[8];
    #pragma unroll
    for (int j = 0; j < 8; ++j) rv[j] = NEG_INF;
    #pragma unroll
    for (int s = 0; s < 16; ++s) {
      float x = sm[t][s];
      if (x > rv[7]) insert8v(rv, x);
    }
    tau[t] = rv[7];
  }
  __syncthreads();

  // ---- Pass 2: recompute + compact candidates >= tau ----------------------
  const float tl = tau[ln];
  for (int t16 = 0; t16 < 16; ++t16) {
    const ushort* tb = ktile + (size_t)t16 * 2048;
    bf16x8 k0 = *reinterpret_cast<const bf16x8*>(tb +        kg * 8);
    bf16x8 k1 = *reinterpret_cast<const bf16x8*>(tb +  512 + kg * 8);
    bf16x8 k2 = *reinterpret_cast<const bf16x8*>(tb + 1024 + kg * 8);
    bf16x8 k3 = *reinterpret_cast<const bf16x8*>(tb + 1536 + kg * 8);

    f32x16 acc = {0.f, 0.f, 0.f, 0.f, 0.f, 0.f, 0.f, 0.f,
                  0.f, 0.f, 0.f, 0.f, 0.f, 0.f, 0.f, 0.f};
    acc = __builtin_amdgcn_mfma_f32_32x32x16_bf16(k0, qf0, acc, 0, 0, 0);
    acc = __builtin_amdgcn_mfma_f32_32x32x16_bf16(k1, qf1, acc, 0, 0, 0);
    acc = __builtin_amdgcn_mfma_f32_32x32x16_bf16(k2, qf2, acc, 0, 0, 0);
    acc = __builtin_amdgcn_mfma_f32_32x32x16_bf16(k3, qf3, acc, 0, 0, 0);

    const int kb0 = qg * 512 + t16 * 32 + 4 * hi;
#define CHK(r) { float x_ = acc[r]; \
                 if (x_ >= tl) { \
                   int p_ = atomicAdd(&cnt[ln], 1); \
                   if (p_ < CAP) cand[ln][p_] = kb0 + ((r) & 3) + 8 * ((r) >> 2); } }
    CHK(0)  CHK(1)  CHK(2)  CHK(3)
    CHK(4)  CHK(5)  CHK(6)  CHK(7)
    CHK(8)  CHK(9)  CHK(10) CHK(11)
    CHK(12) CHK(13) CHK(14) CHK(15)
#undef CHK
  }
  __syncthreads();

  // ---- exact f32 rescore (bit-identical blocked order) --------------------
  {
    int row = t >> 4, j0 = t & 15;
    int n = min(cnt[row], CAP);
    for (int jj = j0; jj < n; jj += 16) {
      int idx = cand[row][jj];
      const float* kcol = kh + ((size_t)b * NK + idx) * INNER;
      float acc = 0.f;
      #pragma unroll
      for (int dd = 0; dd < INNER; dd += 4) {
        v4f kv = *reinterpret_cast<const v4f*>(kcol + dd);
        v4f qv = *reinterpret_cast<const v4f*>(&qhf[row][dd]);
        float bs = qv[0] * kv[0];
        bs = fmaf(qv[1], kv[1], bs);
        bs = fmaf(qv[2], kv[2], bs);
        bs = fmaf(qv[3], kv[3], bs);
        acc += bs;
      }
      exactv[row][jj] = acc;
    }
  }
  __syncthreads();

  // ---- top-5 of exact scores + softmax ------------------------------------
  if (t < 32) {
    int n = min(cnt[t], CAP);
    float rv[5]; int ri[5];
    #pragma unroll
    for (int j = 0; j < 5; ++j) { rv[j] = NEG_INF; ri[j] = 0; }
    for (int j = 0; j < n; ++j) {
      float x = exactv[t][j];
      if (x > rv[4]) insert5(rv, ri, x, cand[t][j]);
    }
    bool inc4 = (rv[4] >= rv[3]);
    float e1 = expf(rv[1] - rv[0]);
    float e2 = expf(rv[2] - rv[0]);
    float e3 = expf(rv[3] - rv[0]);
    float e4 = inc4 ? expf(rv[4] - rv[0]) : 0.0f;
    float inv = 1.0f / (1.0f + e1 + e2 + e3 + e4);
    w5[t][0] = inv;      w5[t][1] = e1 * inv;  w5[t][2] = e2 * inv;
    w5[t][3] = e3 * inv; w5[t][4] = e4 * inv;
    #pragma unroll
    for (int j = 0; j < 5; ++j) id5[t][j] = ri[j];
    id5[t][5] = inc4 ? 5 : 4;
  }
  __syncthreads();

  // ---- scattered weight stores (zeros written by proj, stream-ordered) ----
  if (t < 160) {
    int row = t / 5, j = t % 5;
    if (j < id5[row][5]) {
      float* obase = out + ((size_t)b * NQ + q0) * (size_t)NK;
      obase[(size_t)row * NK + id5[row][j]] = w5[row][j];
    }
  }
}

extern "C" void kernel_launch(void* const* d_in, const int* in_sizes, int n_in,
                              void* d_out, int out_size, void* d_ws, size_t ws_size,
                              hipStream_t stream) {
  const float* q  = (const float*)d_in[0];
  const float* k  = (const float*)d_in[1];
  const float* Wq = (const float*)d_in[3];
  const float* Wk = (const float*)d_in[4];

  const size_t NE = (size_t)BATCH * NQ * INNER;     // 1,048,576 per array
  float*  qh  = (float*)d_ws;                       // 4 MB
  float*  kh  = qh + NE;                            // 4 MB
  ushort* qhb = (ushort*)(kh + NE);                 // 2 MB
  ushort* khb = qhb + NE;                           // 2 MB (fragment-major)

  proj_kernel<<<1024, 256, 0, stream>>>(q, k, Wq, Wk, qh, kh, qhb, khb,
                                        (float*)d_out);
  filter_kernel<<<512, 512, 0, stream>>>(qhb, khb, qh, kh, (float*)d_out);
}

// Round 13
// 142.827 us; speedup vs baseline: 1.0018x; 1.0018x over previous
//
#include <hip/hip_runtime.h>
#include <hip/hip_bf16.h>
#include <math.h>

typedef float v4f __attribute__((ext_vector_type(4)));
typedef short bf16x8 __attribute__((ext_vector_type(8)));   // 8 bf16 (4 VGPR)
typedef float f32x16 __attribute__((ext_vector_type(16)));

#define BATCH 4
#define NQ 4096
#define NK 4096
#define DIM 256
#define INNER 64
#define NEG_INF (-3.0e38f)
#define CAP 64

// ---------- K1: fused q/k projection (f32 + bf16; khb fragment-major) --------
// grid 1024: bid<512 -> q slab (row-major bf16), else k slab (fragment-major
// bf16: [tile32][d:4][hi:2][row:32][e:8]). Values bit-identical to r2-r12.
__global__ __launch_bounds__(256) void proj_kernel(
    const float* __restrict__ q, const float* __restrict__ k,
    const float* __restrict__ Wq, const float* __restrict__ Wk,
    float* __restrict__ qh, float* __restrict__ kh,
    ushort* __restrict__ qhb, ushort* __restrict__ khb)
{
  __shared__ float xs[32 * 260];
  const int bid = blockIdx.x;
  const bool isq = bid < 512;
  const float* X   = isq ? q : k;
  const float* W   = isq ? Wq : Wk;
  float*   out     = isq ? qh : kh;
  const float scale = isq ? 0.125f : 1.0f;
  const int row0 = (isq ? bid : bid - 512) * 32;
  const int t = threadIdx.x;

  #pragma unroll
  for (int it = 0; it < 8; ++it) {
    int idx = it * 256 + t;
    int r = idx >> 6, dq = idx & 63;
    v4f v = *reinterpret_cast<const v4f*>(X + (size_t)(row0 + r) * DIM + dq * 4);
    *reinterpret_cast<v4f*>(&xs[r * 260 + dq * 4]) = v;
  }
  __syncthreads();

  const int i0 = (t & 15) * 4;
  const int rg = t >> 4;
  float acc[2][4];
  #pragma unroll
  for (int p = 0; p < 2; ++p)
    #pragma unroll
    for (int i = 0; i < 4; ++i) acc[p][i] = 0.f;

  for (int d0 = 0; d0 < DIM; d0 += 4) {
    v4f w0 = *reinterpret_cast<const v4f*>(W + (d0 + 0) * INNER + i0);
    v4f w1 = *reinterpret_cast<const v4f*>(W + (d0 + 1) * INNER + i0);
    v4f w2 = *reinterpret_cast<const v4f*>(W + (d0 + 2) * INNER + i0);
    v4f w3 = *reinterpret_cast<const v4f*>(W + (d0 + 3) * INNER + i0);
    #pragma unroll
    for (int p = 0; p < 2; ++p) {
      v4f x = *reinterpret_cast<const v4f*>(&xs[(rg + 16 * p) * 260 + d0]);
      #pragma unroll
      for (int i = 0; i < 4; ++i) {
        float bs = x[0] * w0[i];                 // bit-exact blocked order
        bs = fmaf(x[1], w1[i], bs);
        bs = fmaf(x[2], w2[i], bs);
        bs = fmaf(x[3], w3[i], bs);
        acc[p][i] += bs;
      }
    }
  }

  const int d  = i0 >> 4;
  const int hi = (i0 >> 3) & 1;
  const int e0 = i0 & 7;
  #pragma unroll
  for (int p = 0; p < 2; ++p) {
    v4f o;
    ushort ob[4];
    #pragma unroll
    for (int i = 0; i < 4; ++i) {
      o[i] = acc[p][i] * scale;
      __hip_bfloat16 h = __float2bfloat16(o[i]);
      ob[i] = *reinterpret_cast<ushort*>(&h);
    }
    int rr = rg + 16 * p;
    size_t row = (size_t)(row0 + rr);
    *reinterpret_cast<v4f*>(out + row * INNER + i0) = o;
    if (isq) {
      *reinterpret_cast<uint2*>(qhb + row * INNER + i0) =
          *reinterpret_cast<uint2*>(ob);
    } else {
      size_t off = (size_t)(bid - 512) * 2048 + d * 512 + hi * 256 + rr * 8 + e0;
      *reinterpret_cast<uint2*>(khb + off) = *reinterpret_cast<uint2*>(ob);
    }
  }
}

// ---------- cold-path sorted inserts -----------------------------------------
__device__ __forceinline__ void insert5(float (&v)[5], int (&ix)[5], float x, int xi) {
  bool g0 = x > v[0], g1 = x > v[1], g2 = x > v[2], g3 = x > v[3];
  v[4]  = g3 ? v[3] : x;                 ix[4] = g3 ? ix[3] : xi;
  v[3]  = g3 ? (g2 ? v[2] : x) : v[3];   ix[3] = g3 ? (g2 ? ix[2] : xi) : ix[3];
  v[2]  = g2 ? (g1 ? v[1] : x) : v[2];   ix[2] = g2 ? (g1 ? ix[1] : xi) : ix[2];
  v[1]  = g1 ? (g0 ? v[0] : x) : v[1];   ix[1] = g1 ? (g0 ? ix[0] : xi) : ix[1];
  v[0]  = g0 ? x : v[0];                 ix[0] = g0 ? xi : ix[0];
}

__device__ __forceinline__ void insert8v(float (&v)[8], float x) {
  bool g0 = x > v[0], g1 = x > v[1], g2 = x > v[2], g3 = x > v[3];
  bool g4 = x > v[4], g5 = x > v[5], g6 = x > v[6];
  v[7] = g6 ? v[6] : x;
  v[6] = g6 ? (g5 ? v[5] : x) : v[6];
  v[5] = g5 ? (g4 ? v[4] : x) : v[5];
  v[4] = g4 ? (g3 ? v[3] : x) : v[4];
  v[3] = g3 ? (g2 ? v[2] : x) : v[3];
  v[2] = g2 ? (g1 ? v[1] : x) : v[2];
  v[1] = g1 ? (g0 ? v[0] : x) : v[1];
  v[0] = g0 ? x : v[0];
}

// ---------- K2: wave-specialized filter --------------------------------------
// 768 thr = 12 waves. Waves 0-7 (t<512): 2-pass MFMA filter + exact rescore +
// softmax + sparse scatter (unchanged, validated r9-r12). Waves 8-11 (t>=512):
// zero-fill the block's own 32 output rows (512 KB) with NONTEMPORAL stores —
// independent per-wave vmcnt => zero coupling with compute waves' load waits.
// Both branches execute exactly 5 __syncthreads; each wave drains its own
// stores at its barrier, so zeros are globally visible before the scatter
// (which runs after barrier #5).
__global__ __launch_bounds__(768) void filter_kernel(
    const ushort* __restrict__ qhb, const ushort* __restrict__ khb,
    const float* __restrict__ qh, const float* __restrict__ kh,
    float* __restrict__ out)
{
  __shared__ float qhf[32][68];
  __shared__ float sm[32][16];
  __shared__ float tau[32];
  __shared__ int   cnt[32];
  __shared__ int   cand[32][CAP];
  __shared__ float exactv[32][CAP];
  __shared__ float w5[32][5];
  __shared__ int   id5[32][6];

  const int t   = threadIdx.x;
  const int bid = blockIdx.x;
  const int wg  = (bid & 7) * 64 + (bid >> 3);   // XCD swizzle (512 = 8*64)
  const int b   = wg >> 7;
  const int q0  = (wg & 127) * 32;

  float* obase = out + ((size_t)b * NQ + q0) * (size_t)NK;
  const v4f z = {0.f, 0.f, 0.f, 0.f};

  if (t < 512) {
    // ===================== compute waves (0-7) ============================
    const int qg  = t >> 6;                      // wave 0..7
    const int kg  = t & 63;
    const int ln  = kg & 31;
    const int hi  = kg >> 5;

    if (t < 256) {
      int row = t >> 3, c8 = (t & 7) * 8;
      const float* src = qh + ((size_t)b * NQ + q0 + row) * INNER + c8;
      *reinterpret_cast<v4f*>(&qhf[row][c8])     = *reinterpret_cast<const v4f*>(src);
      *reinterpret_cast<v4f*>(&qhf[row][c8 + 4]) = *reinterpret_cast<const v4f*>(src + 4);
    }
    if (t < 32) cnt[t] = 0;

    const ushort* qptr = qhb + ((size_t)b * NQ + q0 + ln) * INNER + hi * 8;
    bf16x8 qf0 = *reinterpret_cast<const bf16x8*>(qptr);
    bf16x8 qf1 = *reinterpret_cast<const bf16x8*>(qptr + 16);
    bf16x8 qf2 = *reinterpret_cast<const bf16x8*>(qptr + 32);
    bf16x8 qf3 = *reinterpret_cast<const bf16x8*>(qptr + 48);

    const ushort* ktile = khb + ((size_t)b * 128 + qg * 16) * 2048;

    // ---- Pass 1: branchless strip max ------------------------------------
    float smax = NEG_INF;
    for (int t16 = 0; t16 < 16; ++t16) {
      const ushort* tb = ktile + (size_t)t16 * 2048;
      bf16x8 k0 = *reinterpret_cast<const bf16x8*>(tb +        kg * 8);
      bf16x8 k1 = *reinterpret_cast<const bf16x8*>(tb +  512 + kg * 8);
      bf16x8 k2 = *reinterpret_cast<const bf16x8*>(tb + 1024 + kg * 8);
      bf16x8 k3 = *reinterpret_cast<const bf16x8*>(tb + 1536 + kg * 8);

      f32x16 acc = {0.f, 0.f, 0.f, 0.f, 0.f, 0.f, 0.f, 0.f,
                    0.f, 0.f, 0.f, 0.f, 0.f, 0.f, 0.f, 0.f};
      acc = __builtin_amdgcn_mfma_f32_32x32x16_bf16(k0, qf0, acc, 0, 0, 0);
      acc = __builtin_amdgcn_mfma_f32_32x32x16_bf16(k1, qf1, acc, 0, 0, 0);
      acc = __builtin_amdgcn_mfma_f32_32x32x16_bf16(k2, qf2, acc, 0, 0, 0);
      acc = __builtin_amdgcn_mfma_f32_32x32x16_bf16(k3, qf3, acc, 0, 0, 0);

      float m0 = fmaxf(fmaxf(acc[0],  acc[1]),  fmaxf(acc[2],  acc[3]));
      float m1 = fmaxf(fmaxf(acc[4],  acc[5]),  fmaxf(acc[6],  acc[7]));
      float m2 = fmaxf(fmaxf(acc[8],  acc[9]),  fmaxf(acc[10], acc[11]));
      float m3 = fmaxf(fmaxf(acc[12], acc[13]), fmaxf(acc[14], acc[15]));
      smax = fmaxf(smax, fmaxf(fmaxf(m0, m1), fmaxf(m2, m3)));
    }
    sm[ln][qg * 2 + hi] = smax;
    __syncthreads();                                           // barrier 1

    if (t < 32) {
      float rv[8];
      #pragma unroll
      for (int j = 0; j < 8; ++j) rv[j] = NEG_INF;
      #pragma unroll
      for (int s = 0; s < 16; ++s) {
        float x = sm[t][s];
        if (x > rv[7]) insert8v(rv, x);
      }
      tau[t] = rv[7];
    }
    __syncthreads();                                           // barrier 2

    // ---- Pass 2: recompute + compact candidates >= tau -------------------
    const float tl = tau[ln];
    for (int t16 = 0; t16 < 16; ++t16) {
      const ushort* tb = ktile + (size_t)t16 * 2048;
      bf16x8 k0 = *reinterpret_cast<const bf16x8*>(tb +        kg * 8);
      bf16x8 k1 = *reinterpret_cast<const bf16x8*>(tb +  512 + kg * 8);
      bf16x8 k2 = *reinterpret_cast<const bf16x8*>(tb + 1024 + kg * 8);
      bf16x8 k3 = *reinterpret_cast<const bf16x8*>(tb + 1536 + kg * 8);

      f32x16 acc = {0.f, 0.f, 0.f, 0.f, 0.f, 0.f, 0.f, 0.f,
                    0.f, 0.f, 0.f, 0.f, 0.f, 0.f, 0.f, 0.f};
      acc = __builtin_amdgcn_mfma_f32_32x32x16_bf16(k0, qf0, acc, 0, 0, 0);
      acc = __builtin_amdgcn_mfma_f32_32x32x16_bf16(k1, qf1, acc, 0, 0, 0);
      acc = __builtin_amdgcn_mfma_f32_32x32x16_bf16(k2, qf2, acc, 0, 0, 0);
      acc = __builtin_amdgcn_mfma_f32_32x32x16_bf16(k3, qf3, acc, 0, 0, 0);

      const int kb0 = qg * 512 + t16 * 32 + 4 * hi;
#define CHK(r) { float x_ = acc[r]; \
                 if (x_ >= tl) { \
                   int p_ = atomicAdd(&cnt[ln], 1); \
                   if (p_ < CAP) cand[ln][p_] = kb0 + ((r) & 3) + 8 * ((r) >> 2); } }
      CHK(0)  CHK(1)  CHK(2)  CHK(3)
      CHK(4)  CHK(5)  CHK(6)  CHK(7)
      CHK(8)  CHK(9)  CHK(10) CHK(11)
      CHK(12) CHK(13) CHK(14) CHK(15)
#undef CHK
    }
    __syncthreads();                                           // barrier 3

    // ---- exact f32 rescore (bit-identical blocked order) -----------------
    {
      int row = t >> 4, j0 = t & 15;
      int n = min(cnt[row], CAP);
      for (int jj = j0; jj < n; jj += 16) {
        int idx = cand[row][jj];
        const float* kcol = kh + ((size_t)b * NK + idx) * INNER;
        float acc = 0.f;
        #pragma unroll
        for (int dd = 0; dd < INNER; dd += 4) {
          v4f kv = *reinterpret_cast<const v4f*>(kcol + dd);
          v4f qv = *reinterpret_cast<const v4f*>(&qhf[row][dd]);
          float bs = qv[0] * kv[0];
          bs = fmaf(qv[1], kv[1], bs);
          bs = fmaf(qv[2], kv[2], bs);
          bs = fmaf(qv[3], kv[3], bs);
          acc += bs;
        }
        exactv[row][jj] = acc;
      }
    }
    __syncthreads();                                           // barrier 4

    // ---- top-5 of exact scores + softmax ---------------------------------
    if (t < 32) {
      int n = min(cnt[t], CAP);
      float rv[5]; int ri[5];
      #pragma unroll
      for (int j = 0; j < 5; ++j) { rv[j] = NEG_INF; ri[j] = 0; }
      for (int j = 0; j < n; ++j) {
        float x = exactv[t][j];
        if (x > rv[4]) insert5(rv, ri, x, cand[t][j]);
      }
      bool inc4 = (rv[4] >= rv[3]);
      float e1 = expf(rv[1] - rv[0]);
      float e2 = expf(rv[2] - rv[0]);
      float e3 = expf(rv[3] - rv[0]);
      float e4 = inc4 ? expf(rv[4] - rv[0]) : 0.0f;
      float inv = 1.0f / (1.0f + e1 + e2 + e3 + e4);
      w5[t][0] = inv;      w5[t][1] = e1 * inv;  w5[t][2] = e2 * inv;
      w5[t][3] = e3 * inv; w5[t][4] = e4 * inv;
      #pragma unroll
      for (int j = 0; j < 5; ++j) id5[t][j] = ri[j];
      id5[t][5] = inc4 ? 5 : 4;
    }
    __syncthreads();                                           // barrier 5

    // ---- scattered weight stores (zero waves drained at their barrier 5) -
    if (t < 160) {
      int row = t / 5, j = t % 5;
      if (j < id5[row][5])
        obase[(size_t)row * NK + id5[row][j]] = w5[row][j];
    }
  } else {
    // ===================== zero-fill waves (8-11) =========================
    // 32 rows x 4096 f32 = 32768 v4f; 256 threads x 128 iters, nontemporal.
    const int tz = t - 512;
    v4f* zp = reinterpret_cast<v4f*>(obase);
    int it = 0;
    #pragma unroll 2
    for (int u = 0; u < 26; ++u, ++it)
      __builtin_nontemporal_store(z, zp + it * 256 + tz);
    __syncthreads();                                           // barrier 1
    #pragma unroll 2
    for (int u = 0; u < 26; ++u, ++it)
      __builtin_nontemporal_store(z, zp + it * 256 + tz);
    __syncthreads();                                           // barrier 2
    #pragma unroll 2
    for (int u = 0; u < 26; ++u, ++it)
      __builtin_nontemporal_store(z, zp + it * 256 + tz);
    __syncthreads();                                           // barrier 3
    #pragma unroll 2
    for (int u = 0; u < 25; ++u, ++it)
      __builtin_nontemporal_store(z, zp + it * 256 + tz);
    __syncthreads();                                           // barrier 4
    #pragma unroll 2
    for (int u = 0; u < 25; ++u, ++it)
      __builtin_nontemporal_store(z, zp + it * 256 + tz);
    __syncthreads();                                           // barrier 5
  }
}

extern "C" void kernel_launch(void* const* d_in, const int* in_sizes, int n_in,
                              void* d_out, int out_size, void* d_ws, size_t ws_size,
                              hipStream_t stream) {
  const float* q  = (const float*)d_in[0];
  const float* k  = (const float*)d_in[1];
  const float* Wq = (const float*)d_in[3];
  const float* Wk = (const float*)d_in[4];

  const size_t NE = (size_t)BATCH * NQ * INNER;     // 1,048,576 per array
  float*  qh  = (float*)d_ws;                       // 4 MB
  float*  kh  = qh + NE;                            // 4 MB
  ushort* qhb = (ushort*)(kh + NE);                 // 2 MB
  ushort* khb = qhb + NE;                           // 2 MB (fragment-major)

  proj_kernel<<<1024, 256, 0, stream>>>(q, k, Wq, Wk, qh, kh, qhb, khb);
  filter_kernel<<<512, 768, 0, stream>>>(qhb, khb, qh, kh, (float*)d_out);
}